// Round 13
// baseline (190.977 us; speedup 1.0000x reference)
//
#include <hip/hip_runtime.h>
#include <hip/hip_bf16.h>
#include <math.h>

// GNO collapsed: h = lift(x); per layer h = gelu(h@weff + beff) where
//   weff = Wb + c0*Wq@M, beff = bb + c0*bq@M,
//   M = Wk^T G Wv + (Wk^T s) bv^T + bk (s^T Wv) + N bk bv^T, G = h^T h, s = h^T 1.
// Round 13 (on round-12 passing kernel): (1) G/s-partials in per-LAYER
// generation buffers -- producers store sc (write-through), consumers read with
// plain CACHED loads (first-touch per launch; kernel-start acquire invalidates
// L2) -- removes the serialized sc re-read of 4 MB/layer; (2) G partials in
// fp16 (half the coherent-fabric bytes; error ~1e-6 at output, 1-ulp-safe);
// (3) per-batch flag sets decouple the two batch pipelines; sleep 8->2.

#define NLAYER 4
#define NB 2
#define NN 4096
#define DD 64
#define RPB 32              // rows per block (8192 rows / 256 blocks)
#define NT 256
#define NBLK 256
#define PPB 128             // G-partial slots per batch
#define C0F (1.0f/32768.0f) // (1/sqrt(64))/4096
#define SHP 68              // padded LDS stride
#define SCRN 5320           // scratch floats

typedef __hip_bfloat16 bf16;
typedef unsigned long long u64t;

__device__ __forceinline__ float b2f(const bf16 v) { return __bfloat162float(v); }

template <typename T> struct Acc;
template <> struct Acc<float> {
    static __device__ __forceinline__ float ld(const void* p, int i) { return ((const float*)p)[i]; }
    static __device__ __forceinline__ void st(void* p, int i, float v) { ((float*)p)[i] = v; }
};
template <> struct Acc<bf16> {
    static __device__ __forceinline__ float ld(const void* p, int i) { return b2f(((const bf16*)p)[i]); }
    static __device__ __forceinline__ void st(void* p, int i, float v) { ((bf16*)p)[i] = __float2bfloat16(v); }
};

__device__ __forceinline__ float gelu_exact(float x) {
    return 0.5f * x * (1.0f + erff(x * 0.70710678118654752f));
}

// ---- device-coherent access helpers (agent scope, relaxed) ----
__device__ __forceinline__ void stc(float* p, float v) {
    __hip_atomic_store((unsigned*)p, __float_as_uint(v), __ATOMIC_RELAXED, __HIP_MEMORY_SCOPE_AGENT);
}
__device__ __forceinline__ void stc2(float* p, float a, float b) {
    u64t v = ((u64t)__float_as_uint(b) << 32) | (u64t)__float_as_uint(a);
    __hip_atomic_store((u64t*)p, v, __ATOMIC_RELAXED, __HIP_MEMORY_SCOPE_AGENT);
}
__device__ __forceinline__ void stc64(u64t* p, u64t v) {
    __hip_atomic_store(p, v, __ATOMIC_RELAXED, __HIP_MEMORY_SCOPE_AGENT);
}
__device__ __forceinline__ unsigned ldw(unsigned* p) {
    return __hip_atomic_load(p, __ATOMIC_RELAXED, __HIP_MEMORY_SCOPE_AGENT);
}
__device__ __forceinline__ void stw(unsigned* p, unsigned v) {
    __hip_atomic_store(p, v, __ATOMIC_RELAXED, __HIP_MEMORY_SCOPE_AGENT);
}
// Poll epoch word until >= ep. Producer's __syncthreads (vmcnt(0) per wave)
// precedes its flag store, so flag-visibility implies data-visibility at the
// coherence point; consumers' reads follow a __syncthreads (compiler barrier).
__device__ __forceinline__ void pollw(unsigned* p, unsigned ep) {
    int guard = 0;
    while (ldw(p) < ep && ++guard < (1 << 18)) __builtin_amdgcn_s_sleep(2);
}

union HU { u64t u; _Float16 h[4]; };

// G-partial (fp16) + s-partial (fp32): compute 4x4 tiles, scatter to LDS,
// wave-linear u64 sc copy (full-line write combining at the coherence point).
__device__ __forceinline__ void accG_part(const float (*sH)[SHP], float* scr, int t,
                                          _Float16* __restrict__ Gp, float* __restrict__ sp)
{
    _Float16* scrH = (_Float16*)scr;        // 4096 halves = 8 KB
    float* scrS = scr + 2048;               // 64 floats (byte offset 8192)
    const int tr4 = (t >> 4) << 2, tc4 = (t & 15) << 2;
    float m[4][4];
    #pragma unroll
    for (int a = 0; a < 4; a++)
        #pragma unroll
        for (int b = 0; b < 4; b++) m[a][b] = 0.f;
    #pragma unroll 8
    for (int n = 0; n < RPB; n++) {
        float4 he = *(const float4*)&sH[n][tr4];
        float4 hc = *(const float4*)&sH[n][tc4];
        float ha[4] = {he.x, he.y, he.z, he.w};
        float ca[4] = {hc.x, hc.y, hc.z, hc.w};
        #pragma unroll
        for (int a = 0; a < 4; a++)
            #pragma unroll
            for (int b = 0; b < 4; b++) m[a][b] += ha[a] * ca[b];
    }
    #pragma unroll
    for (int a = 0; a < 4; a++)
        #pragma unroll
        for (int b = 0; b < 4; b++)
            scrH[(tr4 + a) * DD + tc4 + b] = (_Float16)m[a][b];
    if (t < DD) {
        float ss = 0.f;
        #pragma unroll 8
        for (int n = 0; n < RPB; n++) ss += sH[n][t];
        scrS[t] = ss;
    }
    __syncthreads();
    {   // 4096 halves = 512 u64 words; 256 threads x 2, wave-linear
        const u64t* src = (const u64t*)scrH;
        u64t* dst = (u64t*)Gp;
        stc64(&dst[t], src[t]);
        stc64(&dst[t + 256], src[t + 256]);
    }
    if (t < 32) stc2(&sp[2 * t], scrS[2 * t], scrS[2 * t + 1]);
}

// setup: weff/beff column-stripe (4 cols) for (batch bb, stripe S).
// One 17 KB LDS buffer W staged sequentially with G -> Wk -> Wq.
// Gg/sg read with normal cached loads (per-layer unique addresses).
template <typename T>
__device__ void setup_body(const float* Ggl, const float* sgl,
    const void* wq, const void* bq, const void* wb, const void* bbv,
    const void* wk, const void* bk, const void* wv, const void* bv,
    float* wel, float* bel, int layer, int t, int bb, int S, float* scr)
{
    float (*W)[SHP]  = (float(*)[SHP])scr;
    float (*tS)[4]   = (float(*)[4])(scr + 4352);
    float (*mS)[4]   = (float(*)[4])(scr + 4608);
    float (*wvS)[4]  = (float(*)[4])(scr + 4864);
    float* sS  = scr + 5120;
    float* bkS = scr + 5184;
    float* bqS = scr + 5248;
    float* suS = scr + 5312;
    float* bvS = scr + 5316;

    const int wOff = layer * DD * DD, bOff = layer * DD;
    {   // stage G via cached float4 loads
        const float4* gb4 = (const float4*)(Ggl + (size_t)bb * DD * DD);
        for (int i = t; i < DD * DD / 4; i += NT) {
            float4 v = gb4[i];
            const int idx = 4 * i;
            *(float4*)&W[idx >> 6][idx & 63] = v;
        }
    }
    for (int i = t; i < DD * 4; i += NT)
        wvS[i >> 2][i & 3] = Acc<T>::ld(wv, wOff + (i >> 2) * DD + S + (i & 3));
    if (t < DD) {
        sS[t]  = sgl[bb * DD + t];          // cached
        bkS[t] = Acc<T>::ld(bk, bOff + t);
        bqS[t] = Acc<T>::ld(bq, bOff + t);
    }
    if (t < 4) bvS[t] = Acc<T>::ld(bv, bOff + S + t);
    __syncthreads();

    const int r = t >> 2, j = t & 3;
    // P1: T'[:,S] = G.Wv[:,S] + s bv^T  (W = G, symmetric -> row read)
    {
        float a0 = 0.f, a1 = 0.f, a2 = 0.f, a3 = 0.f;
        for (int e = 0; e < DD; e += 4) {
            a0 += W[r][e]     * wvS[e][j];
            a1 += W[r][e + 1] * wvS[e + 1][j];
            a2 += W[r][e + 2] * wvS[e + 2][j];
            a3 += W[r][e + 3] * wvS[e + 3][j];
        }
        tS[r][j] = (a0 + a1) + (a2 + a3) + sS[r] * bvS[j];
        if (t < 4) {
            float u0 = 0.f;
            for (int d = 0; d < DD; d++) u0 += sS[d] * wvS[d][t];
            suS[t] = u0 + (float)NN * bvS[t];
        }
    }
    __syncthreads();
    for (int i = t; i < DD * DD; i += NT) W[i >> 6][i & 63] = Acc<T>::ld(wk, wOff + i);
    __syncthreads();
    // P2: M[:,S] = Wk^T.T' + bk su^T   (W = Wk)
    {
        float a0 = 0.f, a1 = 0.f, a2 = 0.f, a3 = 0.f;
        for (int d = 0; d < DD; d += 4) {
            a0 += W[d][r]     * tS[d][j];
            a1 += W[d + 1][r] * tS[d + 1][j];
            a2 += W[d + 2][r] * tS[d + 2][j];
            a3 += W[d + 3][r] * tS[d + 3][j];
        }
        mS[r][j] = (a0 + a1) + (a2 + a3) + bkS[r] * suS[j];
    }
    __syncthreads();
    for (int i = t; i < DD * DD; i += NT) W[i >> 6][i & 63] = Acc<T>::ld(wq, wOff + i);
    __syncthreads();
    // P3: weff[:,S] = Wb[:,S] + C0*Wq.M[:,S]; beff[S] = bb[S] + C0*bq.M[:,S]
    {
        float a0 = 0.f, a1 = 0.f, a2 = 0.f, a3 = 0.f;
        for (int e = 0; e < DD; e += 4) {
            a0 += W[r][e]     * mS[e][j];
            a1 += W[r][e + 1] * mS[e + 1][j];
            a2 += W[r][e + 2] * mS[e + 2][j];
            a3 += W[r][e + 3] * mS[e + 3][j];
        }
        stc(&wel[bb * DD * DD + r * DD + S + j],
            Acc<T>::ld(wb, wOff + r * DD + S + j) + C0F * ((a0 + a1) + (a2 + a3)));
        if (t < 4) {
            float u = 0.f;
            for (int e = 0; e < DD; e++) u += bqS[e] * mS[e][t];
            stc(&bel[bb * DD + S + t], Acc<T>::ld(bbv, bOff + S + t) + C0F * u);
        }
    }
}

template <typename T>
__device__ void run_net(
    const void* x, const void* lw, const void* lb,
    const void* blkw, const void* blkb,
    const void* qw, const void* qb, const void* kw, const void* kb,
    const void* vw, const void* vb, const void* pw, const void* pb,
    void* out, _Float16* Gpart, float* spart, float* Gg, float* sg,
    float* weff, float* beff, unsigned* bar,
    float (*sH)[SHP], float* scr, int blk, int t)
{
    unsigned* aflag = bar;            // [256] apply/lift done epochs
    unsigned* cflag = bar + 256;      // [130]: [b*64+row] G-combine; [128+b] s
    unsigned* sflag = bar + 392;      // [32]  setup done epochs

    const int row0 = blk * RPB;
    const int bb = row0 >> 12;
    const int r = t >> 4, c4 = (t & 15) << 2;
    const size_t GPG = (size_t)NBLK * DD * DD;   // halves per Gpart generation
    const size_t SPG = (size_t)NBLK * DD;        // floats per spart generation

    // ---- lift: h rows into resident LDS; write gen-0 partials ----
    #pragma unroll
    for (int a = 0; a < 2; a++) {
        const int row = r + 16 * a, gr = row0 + row;
        float x0 = Acc<T>::ld(x, gr * 3 + 0);
        float x1 = Acc<T>::ld(x, gr * 3 + 1);
        float x2 = Acc<T>::ld(x, gr * 3 + 2);
        float o[4];
        #pragma unroll
        for (int b = 0; b < 4; b++) {
            int c = c4 + b;
            o[b] = Acc<T>::ld(lb, c) + x0 * Acc<T>::ld(lw, c)
                 + x1 * Acc<T>::ld(lw, DD + c) + x2 * Acc<T>::ld(lw, 2 * DD + c);
        }
        *(float4*)&sH[row][c4] = make_float4(o[0], o[1], o[2], o[3]);
    }
    __syncthreads();
    accG_part(sH, scr, t, Gpart + (size_t)blk * DD * DD, spart + (size_t)blk * DD);
    __syncthreads();                        // all partial stores drained (vmcnt 0)
    if (t == 0) stw(&aflag[blk], 1u);

    for (int layer = 0; layer < NLAYER; layer++) {
        const unsigned ep = (unsigned)(layer + 1);
        const _Float16* Gpl = Gpart + (size_t)layer * GPG;   // gen read this layer
        const float* spl = spart + (size_t)layer * SPG;
        float* Ggl = Gg + (size_t)layer * NB * DD * DD;
        float* sgl = sg + (size_t)layer * NB * DD;
        float* wel = weff + (size_t)layer * NB * DD * DD;
        float* bel = beff + (size_t)layer * NB * DD;

        // ---- combine G (blocks 0..127): own batch's 128 partials, cached ----
        if (blk < 2 * DD) {
            const int batch = blk >> 6, grow = blk & 63;
            if (t < PPB) pollw(&aflag[batch * PPB + t], ep);
            __syncthreads();
            float (*red)[DD] = (float(*)[DD])scr;   // [16][64]
            const int w = t & 15, kq = t >> 4;      // u64 word 0..15, 16 k-groups
            const u64t* gb = (const u64t*)Gpl;      // plain cached loads
            float a0 = 0.f, a1 = 0.f, a2 = 0.f, a3 = 0.f;
            #pragma unroll
            for (int k = 0; k < 8; k++) {
                HU v;
                v.u = gb[(size_t)(batch * PPB + kq * 8 + k) * 512 + grow * 16 + w];
                a0 += (float)v.h[0]; a1 += (float)v.h[1];
                a2 += (float)v.h[2]; a3 += (float)v.h[3];
            }
            red[kq][4 * w] = a0; red[kq][4 * w + 1] = a1;
            red[kq][4 * w + 2] = a2; red[kq][4 * w + 3] = a3;
            __syncthreads();
            if (t < 32) {
                float s0 = 0.f, s1 = 0.f;
                #pragma unroll
                for (int g = 0; g < 16; g++) { s0 += red[g][2 * t]; s1 += red[g][2 * t + 1]; }
                stc2(&Ggl[batch * DD * DD + grow * DD + 2 * t], s0, s1);
            }
            __syncthreads();                // Gg stores drained
            if (t == 0) stw(&cflag[blk], ep);
        }
        // ---- combine s (blocks 128..129): cached float2 reads ----
        else if (blk < 2 * DD + NB) {
            const int batch = blk - 2 * DD;
            if (t < PPB) pollw(&aflag[batch * PPB + t], ep);
            __syncthreads();
            float (*red)[DD] = (float(*)[DD])scr;   // [8][64]
            const int cp = t & 31, kg = t >> 5;
            float ax = 0.f, ay = 0.f;
            #pragma unroll 4
            for (int k = 0; k < 16; k++) {
                float2 v = *(const float2*)&spl[(size_t)(batch * PPB + kg * 16 + k) * DD + 2 * cp];
                ax += v.x; ay += v.y;
            }
            red[kg][2 * cp] = ax; red[kg][2 * cp + 1] = ay;
            __syncthreads();
            if (t < 32) {
                float s0 = 0.f, s1 = 0.f;
                #pragma unroll
                for (int g = 0; g < 8; g++) { s0 += red[g][2 * t]; s1 += red[g][2 * t + 1]; }
                stc2(&sgl[batch * DD + 2 * t], s0, s1);
            }
            __syncthreads();                // sg stores drained
            if (t == 0) stw(&cflag[2 * DD + batch], ep);
        }

        // ---- setup (blocks 130..161): own batch's 65 combine flags ----
        if (blk >= 2 * DD + NB && blk < 2 * DD + NB + NB * 16) {
            const int sb = blk - (2 * DD + NB);
            const int sbb = sb >> 4;
            if (t < DD) pollw(&cflag[sbb * DD + t], ep);
            else if (t == DD) pollw(&cflag[2 * DD + sbb], ep);
            __syncthreads();
            setup_body<T>(Ggl, sgl, qw, qb, blkw, blkb, kw, kb, vw, vb,
                          wel, bel, layer, t, sbb, (sb & 15) << 2, scr);
            __syncthreads();                // weff/beff stores drained
            if (t == 0) stw(&sflag[sb], ep);
        }

        // ---- apply (all blocks): wait own batch's 16 weff stripes ----
        {
            if (t < 16) pollw(&sflag[bb * 16 + t], ep);
            __syncthreads();
            float (*wE)[DD] = (float(*)[DD])scr;
            float* beS = scr + DD * DD;
            {   // cached float4 staging (per-layer unique addresses)
                const float4* ws4 = (const float4*)(wel + (size_t)bb * DD * DD);
                float4* wd4 = (float4*)&wE[0][0];
                for (int i = t; i < DD * DD / 4; i += NT) wd4[i] = ws4[i];
            }
            if (t < DD) beS[t] = bel[bb * DD + t];   // cached
            __syncthreads();

            float o[2][4];
            #pragma unroll
            for (int a = 0; a < 2; a++) {
                const int row = r + 16 * a;
                float acc[4];
                #pragma unroll
                for (int b = 0; b < 4; b++) acc[b] = beS[c4 + b];
                for (int d = 0; d < DD; d++) {
                    float hv = sH[row][d];
                    float4 w4 = *(const float4*)&wE[d][c4];
                    acc[0] += hv * w4.x; acc[1] += hv * w4.y;
                    acc[2] += hv * w4.z; acc[3] += hv * w4.w;
                }
                #pragma unroll
                for (int b = 0; b < 4; b++) o[a][b] = gelu_exact(acc[b]);
            }

            if (layer == NLAYER - 1) {
                float pbv = Acc<T>::ld(pb, 0);
                #pragma unroll
                for (int a = 0; a < 2; a++) {
                    float p = 0.f;
                    #pragma unroll
                    for (int b = 0; b < 4; b++) p += o[a][b] * Acc<T>::ld(pw, c4 + b);
                    p += __shfl_xor(p, 1);
                    p += __shfl_xor(p, 2);
                    p += __shfl_xor(p, 4);
                    p += __shfl_xor(p, 8);
                    if ((t & 15) == 0) Acc<T>::st(out, row0 + r + 16 * a, p + pbv);
                }
            } else {
                __syncthreads();            // wE/beS/sH reads done before overwrite
                #pragma unroll
                for (int a = 0; a < 2; a++)
                    *(float4*)&sH[r + 16 * a][c4] =
                        make_float4(o[a][0], o[a][1], o[a][2], o[a][3]);
                __syncthreads();
                accG_part(sH, scr, t,
                          Gpart + (size_t)(layer + 1) * GPG + (size_t)blk * DD * DD,
                          spart + (size_t)(layer + 1) * SPG + (size_t)blk * DD);
                __syncthreads();            // partial stores drained
                if (t == 0) stw(&aflag[blk], ep + 1u);
            }
        }
    }
}

__global__ __launch_bounds__(NT) void gno_kernel(
    const void* x, const void* lw, const void* lb,
    const void* blkw, const void* blkb,
    const void* qw, const void* qb, const void* kw, const void* kb,
    const void* vw, const void* vb, const void* pw, const void* pb,
    void* out, void* GpartV, float* spart, float* Gg, float* sg,
    float* weff, float* beff, unsigned* bar)
{
    __shared__ alignas(16) float sH[RPB][SHP];   //  8704 B: resident h rows
    __shared__ alignas(16) float scr[SCRN];      // 21280 B: phase-union scratch
    __shared__ int stot;

    const int blk = blockIdx.x, t = threadIdx.x;

    // dtype detect: every block scans the same 8192 words -> same answer
    if (t == 0) stot = 0;
    __syncthreads();
    int cnt = 0;
    const unsigned int* xw = (const unsigned int*)x;
    for (int i = t; i < 8192; i += NT) {
        unsigned u = xw[i] & 0xFFFFu;
        int e = (u >> 7) & 0xFF;
        cnt += (u == 0u || (e >= 100 && e <= 142)) ? 1 : 0;
    }
    atomicAdd(&stot, cnt);
    __syncthreads();
    const bool isbf = (stot > 4915);
    _Float16* Gpart = (_Float16*)GpartV;

    if (isbf)
        run_net<bf16>(x, lw, lb, blkw, blkb, qw, qb, kw, kb, vw, vb, pw, pb,
                      out, Gpart, spart, Gg, sg, weff, beff, bar, sH, scr, blk, t);
    else
        run_net<float>(x, lw, lb, blkw, blkb, qw, qb, kw, kb, vw, vb, pw, pb,
                       out, Gpart, spart, Gg, sg, weff, beff, bar, sH, scr, blk, t);
}

extern "C" void kernel_launch(void* const* d_in, const int* in_sizes, int n_in,
                              void* d_out, int out_size, void* d_ws, size_t ws_size,
                              hipStream_t stream)
{
    const void* x    = d_in[0];
    const void* lw   = d_in[1];
    const void* lb   = d_in[2];
    const void* blkw = d_in[3];
    const void* blkb = d_in[4];
    const void* qw   = d_in[5];
    const void* qb   = d_in[6];
    const void* kw   = d_in[7];
    const void* kb   = d_in[8];
    const void* vw   = d_in[9];
    const void* vb   = d_in[10];
    const void* pw   = d_in[11];
    const void* pb   = d_in[12];

    unsigned* bar = (unsigned*)d_ws;                        // [512] flag words
    char* p = (char*)d_ws + 2048;
    void* Gpart = p;                                        // [4 gens][256][64*64] fp16 = 8 MB
    p += (size_t)NLAYER * NBLK * DD * DD * 2;
    float* spart = (float*)p;                               // [4 gens][256][64] fp32
    p += (size_t)NLAYER * NBLK * DD * 4;
    float* Gg = (float*)p;                                  // [4][2][64][64]
    p += (size_t)NLAYER * NB * DD * DD * 4;
    float* sg = (float*)p;                                  // [4][2][64]
    p += (size_t)NLAYER * NB * DD * 4;
    float* weff = (float*)p;                                // [4][2][64][64]
    p += (size_t)NLAYER * NB * DD * DD * 4;
    float* beff = (float*)p;                                // [4][2][64]

    hipMemsetAsync(bar, 0, 512 * sizeof(unsigned), stream);
    gno_kernel<<<NBLK, NT, 0, stream>>>(x, lw, lb, blkw, blkb, qw, qb, kw, kb,
                                        vw, vb, pw, pb, d_out,
                                        Gpart, spart, Gg, sg, weff, beff, bar);
}